// Round 6
// baseline (67.829 us; speedup 1.0000x reference)
//
#include <hip/hip_runtime.h>

#define HOP     256
#define WD      32
#define NFRM    4096
#define TLEN    1048832        // FRAMELEN + HOP*(NFRM-1)
#define LROW    786688         // 448 + 4095*192
#define FPB     8              // frames per block
#define XSTR    484            // x floats per frame (121 quads; 484 % 32 == 4)
#define DSTR    420            // d floats per chain (105 quads; 420 % 32 == 4)
#define XQn     121
#define DQn     105
#define XTOT    (FPB*XSTR + 16)
#define DTOT    (2*FPB*DSTR + 8)

// 16-lane xor-butterfly sum within each row of 16; result in all 16 lanes.
__device__ __forceinline__ float red16(float v) {
    v += __int_as_float(__builtin_amdgcn_update_dpp(0, __float_as_int(v), 0xB1,  0xF, 0xF, true)); // xor1
    v += __int_as_float(__builtin_amdgcn_update_dpp(0, __float_as_int(v), 0x4E,  0xF, 0xF, true)); // xor2
    v += __int_as_float(__builtin_amdgcn_update_dpp(0, __float_as_int(v), 0x141, 0xF, 0xF, true)); // half-mirror
    v += __int_as_float(__builtin_amdgcn_update_dpp(0, __float_as_int(v), 0x140, 0xF, 0xF, true)); // row-mirror
    return v;
}

#define CL(v) __builtin_amdgcn_fmed3f((v), -65535.0f, 65535.0f)

// One LMS step for one set: 4 taps/lane (W0..W3), window X0..X3, desired DV.
#define STEP1(W0,W1,W2,W3, X0,X1,X2,X3, DV, J, SO, EO) do {       \
    float p = W0 * (X0);                                          \
    p = fmaf(W1, (X1), p);                                        \
    p = fmaf(W2, (X2), p);                                        \
    p = fmaf(W3, (X3), p);                                        \
    float s  = red16(p);                                          \
    float e  = (DV) - s;                                          \
    SO = (col == (J)) ? s : SO;                                   \
    EO = (col == (J)) ? e : EO;                                   \
    float gm = 0.05f * e;                                         \
    W0 = CL(fmaf(gm, (X0), W0));                                  \
    W1 = CL(fmaf(gm, (X1), W1));                                  \
    W2 = CL(fmaf(gm, (X2), W2));                                  \
    W3 = CL(fmaf(gm, (X3), W3));                                  \
} while (0)

// One 4-step group (uses x quads QA,QB and d quad DQ4), with store.
#define GROUP4(W0,W1,W2,W3, QA, QB, DQ4, G, EARLY, OD, OE) do {   \
    float so = 0.f, eo = 0.f;                                     \
    STEP1(W0,W1,W2,W3, QA.x,QA.y,QA.z,QA.w, DQ4.x, 0, so, eo);    \
    STEP1(W0,W1,W2,W3, QA.y,QA.z,QA.w,QB.x, DQ4.y, 1, so, eo);    \
    STEP1(W0,W1,W2,W3, QA.z,QA.w,QB.x,QB.y, DQ4.z, 2, so, eo);    \
    STEP1(W0,W1,W2,W3, QA.w,QB.x,QB.y,QB.z, DQ4.w, 3, so, eo);    \
    if (((G) >= 56 || (EARLY)) && col < 4) {                      \
        OD[4*(G)+col] = so; OE[4*(G)+col] = eo; }                 \
} while (0)

// block = 128 threads = 2 waves; each wave runs TWO independent chain-sets
// of 4 chains (L=16) -> 16 chains/block = 8 frames x 2 batches.
__global__ void __launch_bounds__(128, 1)
lms_kernel(const float* __restrict__ dmat, const float* __restrict__ xvec,
           float* __restrict__ out)
{
    __shared__ __align__(16) float lx[XTOT];
    __shared__ __align__(16) float ld[DTOT];

    const int tid = threadIdx.x;
    const int f0  = blockIdx.x * FPB;

    // ---- stage: 968 x-quads + 1680 d-quads ----
    for (int i = tid; i < 968 + 1680; i += 128) {
        if (i < 968) {
            int fr = i / XQn, k = i - fr * XQn;
            ((float4*)lx)[i] =
                *(const float4*)(xvec + (size_t)(f0 + fr) * HOP + 4 * k);
        } else {
            int j = i - 968;
            int idx = j / DQn, k = j - idx * DQn;   // idx = b*8 + r
            int b = idx >> 3, r = idx & 7;
            ((float4*)ld)[j] =
                *(const float4*)(dmat + (size_t)b * TLEN
                                 + (size_t)(f0 + r) * HOP + WD + 4 * k);
        }
    }
    __syncthreads();

    const int lane = tid & 63;
    const int wv   = tid >> 6;             // 0..1
    const int row  = lane >> 4;            // 0..3
    const int col  = lane & 15;            // taps 4*col .. 4*col+3
    const int b    = row & 1;              // batch
    const int flA  = 4 * wv + (row >> 1);      // set A local frame
    const int flB  = flA + 2;                  // set B local frame
    const int fA   = f0 + flA;
    const int fB   = f0 + flB;
    const bool earlyA = (fA == 0);
    const bool earlyB = (fB == 0);

    const float4* __restrict__ xqA = (const float4*)(lx + flA * XSTR + 4 * col);
    const float4* __restrict__ xqB = (const float4*)(lx + flB * XSTR + 4 * col);
    const float4* __restrict__ dqA = (const float4*)(ld + (b * FPB + flA) * DSTR);
    const float4* __restrict__ dqB = (const float4*)(ld + (b * FPB + flB) * DSTR);

    float* odA = out + (size_t)b * LROW + 32 + (size_t)192 * fA;
    float* oeA = odA + 2 * (size_t)LROW;
    float* odB = out + (size_t)b * LROW + 32 + (size_t)192 * fB;
    float* oeB = odB + 2 * (size_t)LROW;

    // leading 32 zeros of the 4 output rows
    if (blockIdx.x == 0) {
        out[(size_t)(tid >> 5) * LROW + (tid & 31)] = 0.0f;
    }

    float aw0=0.f, aw1=0.f, aw2=0.f, aw3=0.f;
    float bw0=0.f, bw1=0.f, bw2=0.f, bw3=0.f;

    // prologue
    float4 aX0 = xqA[0], aX1 = xqA[1];  float4 aD0 = dqA[0];
    float4 bX0 = xqB[0], bX1 = xqB[1];  float4 bD0 = dqB[0];

    for (int j = 0; j < 26; ++j) {
        const int g = 4 * j;
        float4 aX2 = xqA[g+2];  float4 aD1 = dqA[g+1];
        float4 bX2 = xqB[g+2];  float4 bD1 = dqB[g+1];
        GROUP4(aw0,aw1,aw2,aw3, aX0, aX1, aD0, g,   earlyA, odA, oeA);
        GROUP4(bw0,bw1,bw2,bw3, bX0, bX1, bD0, g,   earlyB, odB, oeB);

        float4 aX3 = xqA[g+3];  float4 aD2 = dqA[g+2];
        float4 bX3 = xqB[g+3];  float4 bD2 = dqB[g+2];
        GROUP4(aw0,aw1,aw2,aw3, aX1, aX2, aD1, g+1, earlyA, odA, oeA);
        GROUP4(bw0,bw1,bw2,bw3, bX1, bX2, bD1, g+1, earlyB, odB, oeB);

        aX0 = xqA[g+4];  float4 aD3 = dqA[g+3];
        bX0 = xqB[g+4];  float4 bD3 = dqB[g+3];
        GROUP4(aw0,aw1,aw2,aw3, aX2, aX3, aD2, g+2, earlyA, odA, oeA);
        GROUP4(bw0,bw1,bw2,bw3, bX2, bX3, bD2, g+2, earlyB, odB, oeB);

        aX1 = xqA[g+5];  aD0 = dqA[g+4];
        bX1 = xqB[g+5];  bD0 = dqB[g+4];
        GROUP4(aw0,aw1,aw2,aw3, aX3, aX0, aD3, g+3, earlyA, odA, oeA);
        GROUP4(bw0,bw1,bw2,bw3, bX3, bX0, bD3, g+3, earlyB, odB, oeB);
    }
}

extern "C" void kernel_launch(void* const* d_in, const int* in_sizes, int n_in,
                              void* d_out, int out_size, void* d_ws, size_t ws_size,
                              hipStream_t stream) {
    const float* dmat = (const float*)d_in[0];   // (2, TLEN)
    const float* xvec = (const float*)d_in[1];   // (TLEN,)
    float* out = (float*)d_out;                  // [d_est(2,LROW), e(2,LROW)]

    hipLaunchKernelGGL(lms_kernel, dim3(NFRM / FPB), dim3(128), 0, stream,
                       dmat, xvec, out);
}

// Round 7
// 38.040 us; speedup vs baseline: 1.7831x; 1.7831x over previous
//
#include <hip/hip_runtime.h>

#define HOP     256
#define WD      32
#define NFRM    4096
#define TLEN    1048832        // FRAMELEN + HOP*(NFRM-1)
#define LROW    786688         // 448 + 4095*192
#define FPB     8              // frames per block
#define XSTR    484            // x floats per frame (121 quads; 484 % 32 == 4)
#define DSTR    420            // d floats per chain (105 quads; 420 % 32 == 4)
#define XQn     121
#define DQn     105
#define XTOT    (FPB*XSTR + 16)       // + guard for dead prefetch overrun
#define DTOT    (2*FPB*DSTR + 8)

// 16-lane xor-butterfly sum within each row of 16; result in all 16 lanes.
__device__ __forceinline__ float red16(float v) {
    v += __int_as_float(__builtin_amdgcn_update_dpp(0, __float_as_int(v), 0xB1,  0xF, 0xF, true)); // xor1
    v += __int_as_float(__builtin_amdgcn_update_dpp(0, __float_as_int(v), 0x4E,  0xF, 0xF, true)); // xor2
    v += __int_as_float(__builtin_amdgcn_update_dpp(0, __float_as_int(v), 0x141, 0xF, 0xF, true)); // half-mirror
    v += __int_as_float(__builtin_amdgcn_update_dpp(0, __float_as_int(v), 0x140, 0xF, 0xF, true)); // row-mirror
    return v;
}

#define CL(v) __builtin_amdgcn_fmed3f((v), -65535.0f, 65535.0f)

// One LMS step. GV = 0.05*d (pre-scaled), DV = d.  gm = 0.05*(d - s) via fma.
#define STEP1(X0,X1,X2,X3, DV, GV, J) do {                        \
    float p = w0 * (X0);                                          \
    p = fmaf(w1, (X1), p);                                        \
    p = fmaf(w2, (X2), p);                                        \
    p = fmaf(w3, (X3), p);                                        \
    float s  = red16(p);                                          \
    float gm = fmaf(-0.05f, s, (GV));                             \
    float e  = (DV) - s;                                          \
    so = (col == (J)) ? s : so;                                   \
    eo = (col == (J)) ? e : eo;                                   \
    w0 = CL(fmaf(gm, (X0), w0));                                  \
    w1 = CL(fmaf(gm, (X1), w1));                                  \
    w2 = CL(fmaf(gm, (X2), w2));                                  \
    w3 = CL(fmaf(gm, (X3), w3));                                  \
} while (0)

// One 4-step group from x quads QA,QB plus d quad DQ4 and 0.05*d quad GQ4.
#define GROUP4(QA, QB, DQ4, GQ4, G) do {                          \
    float so = 0.f, eo = 0.f;                                     \
    STEP1(QA.x,QA.y,QA.z,QA.w, DQ4.x, GQ4.x, 0);                  \
    STEP1(QA.y,QA.z,QA.w,QB.x, DQ4.y, GQ4.y, 1);                  \
    STEP1(QA.z,QA.w,QB.x,QB.y, DQ4.z, GQ4.z, 2);                  \
    STEP1(QA.w,QB.x,QB.y,QB.z, DQ4.w, GQ4.w, 3);                  \
    if (((G) >= 56 || early) && col < 4) {                        \
        od[4*(G)+col] = so; oe[4*(G)+col] = eo; }                 \
} while (0)

// block = 256 threads = 4 waves; wave = 4 chains (L=16). 512 blocks ->
// 2 blocks/CU -> 2 waves/SIMD: hardware round-robin hides per-step latency.
__global__ void __launch_bounds__(256, 2)
lms_kernel(const float* __restrict__ dmat, const float* __restrict__ xvec,
           float* __restrict__ out)
{
    __shared__ __align__(16) float lx[XTOT];
    __shared__ __align__(16) float ld[DTOT];
    __shared__ __align__(16) float lg[DTOT];   // 0.05 * d

    const int tid = threadIdx.x;
    const int f0  = blockIdx.x * FPB;

    // ---- stage: 968 x-quads + 1680 d-quads (d and 0.05*d) ----
    for (int i = tid; i < 968 + 1680; i += 256) {
        if (i < 968) {
            int fr = i / XQn, k = i - fr * XQn;
            ((float4*)lx)[i] =
                *(const float4*)(xvec + (size_t)(f0 + fr) * HOP + 4 * k);
        } else {
            int j = i - 968;
            int idx = j / DQn, k = j - idx * DQn;   // idx = b*8 + r
            int b = idx >> 3, r = idx & 7;
            float4 v = *(const float4*)(dmat + (size_t)b * TLEN
                                        + (size_t)(f0 + r) * HOP + WD + 4 * k);
            ((float4*)ld)[j] = v;
            float4 g;
            g.x = 0.05f * v.x; g.y = 0.05f * v.y;
            g.z = 0.05f * v.z; g.w = 0.05f * v.w;
            ((float4*)lg)[j] = g;
        }
    }
    __syncthreads();

    const int lane = tid & 63;
    const int wv   = tid >> 6;             // 0..3
    const int row  = lane >> 4;            // 0..3
    const int col  = lane & 15;            // taps 4*col .. 4*col+3
    const int fl   = 2 * wv + (row >> 1);  // local frame 0..7
    const int b    = row & 1;              // batch
    const int f    = f0 + fl;              // global frame
    const bool early = (f == 0);
    const int ci   = b * FPB + fl;         // chain index in d arrays

    const float4* __restrict__ xq = (const float4*)(lx + fl * XSTR + 4 * col);
    const float4* __restrict__ dq = (const float4*)(ld + ci * DSTR);
    const float4* __restrict__ gq = (const float4*)(lg + ci * DSTR);

    float* od = out + (size_t)b * LROW + 32 + (size_t)192 * f;
    float* oe = od + 2 * (size_t)LROW;

    // leading 32 zeros of the 4 output rows
    if (blockIdx.x == 0 && tid < 128) {
        out[(size_t)(tid >> 5) * LROW + (tid & 31)] = 0.0f;
    }

    float w0 = 0.f, w1 = 0.f, w2 = 0.f, w3 = 0.f;

    // prologue: 2-group lead
    float4 X0 = xq[0], X1 = xq[1], X2 = xq[2];
    float4 D0 = dq[0], G0 = gq[0];
    float4 D1 = dq[1], G1 = gq[1];

    for (int j = 0; j < 26; ++j) {
        const int g = 4 * j;
        float4 X3 = xq[g+3];  float4 D2 = dq[g+2];  float4 G2 = gq[g+2];
        GROUP4(X0, X1, D0, G0, g);

        X0 = xq[g+4];  float4 D3 = dq[g+3];  float4 G3 = gq[g+3];
        GROUP4(X1, X2, D1, G1, g+1);

        X1 = xq[g+5];  D0 = dq[g+4];  G0 = gq[g+4];
        GROUP4(X2, X3, D2, G2, g+2);

        X2 = xq[g+6];  D1 = dq[g+5];  G1 = gq[g+5];
        GROUP4(X3, X0, D3, G3, g+3);
    }
}

extern "C" void kernel_launch(void* const* d_in, const int* in_sizes, int n_in,
                              void* d_out, int out_size, void* d_ws, size_t ws_size,
                              hipStream_t stream) {
    const float* dmat = (const float*)d_in[0];   // (2, TLEN)
    const float* xvec = (const float*)d_in[1];   // (TLEN,)
    float* out = (float*)d_out;                  // [d_est(2,LROW), e(2,LROW)]

    hipLaunchKernelGGL(lms_kernel, dim3(NFRM / FPB), dim3(256), 0, stream,
                       dmat, xvec, out);
}

// Round 8
// 37.010 us; speedup vs baseline: 1.8327x; 1.0278x over previous
//
#include <hip/hip_runtime.h>

#define HOP     256
#define WD      32
#define NFRM    4096
#define TLEN    1048832        // FRAMELEN + HOP*(NFRM-1)
#define LROW    786688         // 448 + 4095*192
#define XSTR    484            // x floats per frame (121 quads; 484 % 32 == 4)
#define DSTR    420            // g floats per chain (105 quads; 420 % 32 == 4)
#define XQn     121
#define DQn     105
#define XTOT    (2*XSTR + 16)  // 984  (+guard for dead prefetch overrun)
#define GTOT    (4*DSTR + 8)   // 1688

// 16-lane xor-butterfly sum within each row of 16; result in all 16 lanes.
__device__ __forceinline__ float red16(float v) {
    v += __int_as_float(__builtin_amdgcn_update_dpp(0, __float_as_int(v), 0xB1,  0xF, 0xF, true)); // xor1
    v += __int_as_float(__builtin_amdgcn_update_dpp(0, __float_as_int(v), 0x4E,  0xF, 0xF, true)); // xor2
    v += __int_as_float(__builtin_amdgcn_update_dpp(0, __float_as_int(v), 0x141, 0xF, 0xF, true)); // half-mirror
    v += __int_as_float(__builtin_amdgcn_update_dpp(0, __float_as_int(v), 0x140, 0xF, 0xF, true)); // row-mirror
    return v;
}

#define CL(v) __builtin_amdgcn_fmed3f((v), -65535.0f, 65535.0f)

// One LMS step. GV = 0.05*d (pre-scaled). gm = fmaf(-0.05, s, GV) = 0.05*e.
// Capture: so += IND * s  (IND is 1.0 in exactly one lane's step per 16).
#define STEP1(Xa,Xb,Xc,Xd, GV, IND) do {                          \
    float p = w0 * (Xa);                                          \
    p = fmaf(w1, (Xb), p);                                        \
    p = fmaf(w2, (Xc), p);                                        \
    p = fmaf(w3, (Xd), p);                                        \
    float s  = red16(p);                                          \
    so = fmaf((IND), s, so);                                      \
    float gm = fmaf(-0.05f, s, (GV));                             \
    w0 = CL(fmaf(gm, (Xa), w0));                                  \
    w1 = CL(fmaf(gm, (Xb), w1));                                  \
    w2 = CL(fmaf(gm, (Xc), w2));                                  \
    w3 = CL(fmaf(gm, (Xd), w3));                                  \
} while (0)

#define GROUP4(QA, QB, GQ, Ia, Ib, Ic, Id) do {                   \
    STEP1(QA.x,QA.y,QA.z,QA.w, GQ.x, Ia);                         \
    STEP1(QA.y,QA.z,QA.w,QB.x, GQ.y, Ib);                         \
    STEP1(QA.z,QA.w,QB.x,QB.y, GQ.z, Ic);                         \
    STEP1(QA.w,QB.x,QB.y,QB.z, GQ.w, Id);                         \
} while (0)

// block = 64 threads = 1 wave = 4 chains (L=16) = 2 frames x 2 batches.
// 2048 blocks -> ~8 blocks/CU; the 2 waves/SIMD come from different blocks
// and de-phase naturally, overlapping each other's DPP-hazard stalls.
__global__ void __launch_bounds__(64, 2)
lms_kernel(const float* __restrict__ dmat, const float* __restrict__ xvec,
           float* __restrict__ out)
{
    __shared__ __align__(16) float lx[XTOT];
    __shared__ __align__(16) float lg[GTOT];   // 0.05 * d, per chain

    const int tid = threadIdx.x;
    const int f0  = blockIdx.x * 2;

    // ---- stage: 242 x-quads + 420 g-quads ----
    for (int i = tid; i < 242 + 420; i += 64) {
        if (i < 242) {
            int fr = (i >= XQn) ? 1 : 0;
            int k  = i - fr * XQn;
            ((float4*)lx)[i] =
                *(const float4*)(xvec + (size_t)(f0 + fr) * HOP + 4 * k);
        } else {
            int j   = i - 242;
            int idx = j / DQn, k = j - idx * DQn;   // idx = b*2 + r
            int b = idx >> 1, r = idx & 1;
            float4 v = *(const float4*)(dmat + (size_t)b * TLEN
                                        + (size_t)(f0 + r) * HOP + WD + 4 * k);
            float4 g2;
            g2.x = 0.05f * v.x; g2.y = 0.05f * v.y;
            g2.z = 0.05f * v.z; g2.w = 0.05f * v.w;
            ((float4*)lg)[j] = g2;
        }
    }
    __syncthreads();

    const int lane = tid & 63;
    const int row  = lane >> 4;            // 0..3
    const int col  = lane & 15;            // taps 4*col .. 4*col+3
    const int fl   = row >> 1;             // local frame 0..1
    const int b    = row & 1;              // batch
    const int f    = f0 + fl;              // global frame
    const bool early = (f == 0);
    const int ci   = b * 2 + fl;           // chain slot in lg

    const float4* __restrict__ xq  = (const float4*)(lx + fl * XSTR + 4 * col);
    const float4* __restrict__ gq  = (const float4*)(lg + ci * DSTR);
    const float*  __restrict__ lgs = lg + ci * DSTR;

    float* od = out + (size_t)b * LROW + 32 + (size_t)192 * f;
    float* oe = od + 2 * (size_t)LROW;

    // leading 32 zeros of the 4 output rows
    if (blockIdx.x == 0) {
        int pos = tid & 31;
        for (int r2 = tid >> 5; r2 < 4; r2 += 2)
            out[(size_t)r2 * LROW + pos] = 0.0f;
    }

    // per-lane step indicators (statically indexed -> stay in registers)
    const float i0  = (col ==  0) ? 1.f : 0.f, i1  = (col ==  1) ? 1.f : 0.f;
    const float i2  = (col ==  2) ? 1.f : 0.f, i3  = (col ==  3) ? 1.f : 0.f;
    const float i4  = (col ==  4) ? 1.f : 0.f, i5  = (col ==  5) ? 1.f : 0.f;
    const float i6  = (col ==  6) ? 1.f : 0.f, i7  = (col ==  7) ? 1.f : 0.f;
    const float i8  = (col ==  8) ? 1.f : 0.f, i9  = (col ==  9) ? 1.f : 0.f;
    const float i10 = (col == 10) ? 1.f : 0.f, i11 = (col == 11) ? 1.f : 0.f;
    const float i12 = (col == 12) ? 1.f : 0.f, i13 = (col == 13) ? 1.f : 0.f;
    const float i14 = (col == 14) ? 1.f : 0.f, i15 = (col == 15) ? 1.f : 0.f;

    float w0 = 0.f, w1 = 0.f, w2 = 0.f, w3 = 0.f;

    // prologue: 2-group lead
    float4 X0 = xq[0], X1 = xq[1], X2 = xq[2];
    float4 G0 = gq[0], G1 = gq[1];

    for (int j = 0; j < 26; ++j) {
        const int g = 4 * j;
        float so  = 0.f;
        float gvs = lgs[16 * j + col];             // for the store-time gm

        float4 X3 = xq[g+3];  float4 G2 = gq[g+2];
        GROUP4(X0, X1, G0, i0,  i1,  i2,  i3);

        X0 = xq[g+4];         float4 G3 = gq[g+3];
        GROUP4(X1, X2, G1, i4,  i5,  i6,  i7);

        X1 = xq[g+5];         G0 = gq[g+4];
        GROUP4(X2, X3, G2, i8,  i9,  i10, i11);

        X2 = xq[g+6];         G1 = gq[g+5];
        GROUP4(X3, X0, G3, i12, i13, i14, i15);

        if (j >= 14 || early) {
            float gms = fmaf(-0.05f, so, gvs);     // == in-loop gm bitwise
            od[16 * j + col] = so;                 // d_est
            oe[16 * j + col] = 20.0f * gms;        // e = 20 * (0.05*e)
        }
    }
}

extern "C" void kernel_launch(void* const* d_in, const int* in_sizes, int n_in,
                              void* d_out, int out_size, void* d_ws, size_t ws_size,
                              hipStream_t stream) {
    const float* dmat = (const float*)d_in[0];   // (2, TLEN)
    const float* xvec = (const float*)d_in[1];   // (TLEN,)
    float* out = (float*)d_out;                  // [d_est(2,LROW), e(2,LROW)]

    hipLaunchKernelGGL(lms_kernel, dim3(NFRM / 2), dim3(64), 0, stream,
                       dmat, xvec, out);
}